// Round 10
// baseline (61.619 us; speedup 1.0000x reference)
//
#include <hip/hip_runtime.h>
#include <math.h>

#define SD 16512            // 128 + 128*128
#define NCH 32              // K-chunks (31 x 512 + 1 x 640)
#define RPSTRIDE 8192       // partial: [rowpair 128][ch 32][col 256] u32
#define LN_EPS 1e-5f

typedef __attribute__((ext_vector_type(4))) float f32x4;
typedef __attribute__((ext_vector_type(8))) short bf16x8;

__device__ __forceinline__ unsigned bfpack(float lo, float hi) {
    unsigned a = __builtin_bit_cast(unsigned, lo);
    unsigned b = __builtin_bit_cast(unsigned, hi);
    a = (a + 0x7FFFu + ((a >> 16) & 1u)) >> 16;
    b = (b + 0x7FFFu + ((b >> 16) & 1u)) >> 16;
    return a | (b << 16);
}
__device__ __forceinline__ unsigned short bf1(float x) {
    unsigned a = __builtin_bit_cast(unsigned, x);
    return (unsigned short)((a + 0x7FFFu + ((a >> 16) & 1u)) >> 16);
}

// ---------------------------------------------------------------------------
// K1: signature via MFMA. grid 257 x 512: blocks 0..255 = batch; 256 = Wd prep.
// ---------------------------------------------------------------------------
__global__ __launch_bounds__(512) void k_sig(const float* __restrict__ x,
                                             const float* __restrict__ tk,
                                             const float* __restrict__ Wd,
                                             unsigned short* __restrict__ sig,
                                             unsigned short* __restrict__ xbf,
                                             unsigned short* __restrict__ WdTg) {
    __shared__ unsigned short Ut[128][72];
    __shared__ unsigned short DXt[128][72];
    __shared__ float tks[64];
    int tid = threadIdx.x;
    int b = blockIdx.x;

    if (b == 256) {
        int d = tid & 127, kh = tid >> 7;          // kh 0..3, 32 k each
        unsigned* dst = (unsigned*)WdTg;
        for (int kk = 0; kk < 32; kk += 2) {
            int k = kh * 32 + kk;
            float v0 = Wd[(size_t)k * 128 + d];
            float v1 = Wd[(size_t)(k + 1) * 128 + d];
            dst[d * 64 + (k >> 1)] = bfpack(v0, v1);
        }
        return;
    }

    if (tid < 64) tks[tid] = tk[tid];
    __syncthreads();

    const float* xb = x + (size_t)b * 8192;
    unsigned short* xbb = xbf + (size_t)b * 8192;
    int i = tid & 127, th = tid >> 7;              // th 0..3, 8 pairs each

    float x0 = tks[0] * xb[i];
    float xa = tks[th * 16] * xb[(size_t)(th * 16) * 128 + i];
    #pragma unroll
    for (int tp = 0; tp < 8; ++tp) {
        int p = th * 8 + tp;
        int t0 = 2 * p;
        float xv = tks[t0 + 1] * xb[(size_t)(t0 + 1) * 128 + i];
        float dx0 = xv - xa, u0 = 0.5f * (xa + xv) - x0;
        float dx1, u1, xc;
        if (p == 31) { dx1 = 0.f; u1 = 0.f; xc = 0.f; }
        else {
            xc = tks[t0 + 2] * xb[(size_t)(t0 + 2) * 128 + i];
            dx1 = xc - xv; u1 = 0.5f * (xv + xc) - x0;
        }
        *(unsigned*)&Ut[i][t0]  = bfpack(u0, u1);
        *(unsigned*)&DXt[i][t0] = bfpack(dx0, dx1);
        xbb[(size_t)t0 * 128 + i]       = bf1(xa);
        xbb[(size_t)(t0 + 1) * 128 + i] = bf1(xv);
        if (p == 31) sig[(size_t)b * SD + i] = bf1(xv - x0);   // S1
        xa = xc;
    }
    __syncthreads();

    // S2 = Ut(128 x 64k) @ DXt^T. 8 waves: 2M x 4N, wave tile 64x32.
    int w = tid >> 6, lane = tid & 63;
    int wm = w >> 2, wn = w & 3;
    int l15 = lane & 15, lg = lane >> 4;
    f32x4 acc[4][2];
    #pragma unroll
    for (int m = 0; m < 4; ++m)
        #pragma unroll
        for (int n = 0; n < 2; ++n) acc[m][n] = (f32x4){0.f, 0.f, 0.f, 0.f};

    #pragma unroll
    for (int ks = 0; ks < 2; ++ks) {
        bf16x8 af[4], bfv[2];
        #pragma unroll
        for (int m = 0; m < 4; ++m)
            af[m] = *(const bf16x8*)&Ut[wm * 64 + m * 16 + l15][ks * 32 + lg * 8];
        #pragma unroll
        for (int n = 0; n < 2; ++n)
            bfv[n] = *(const bf16x8*)&DXt[wn * 32 + n * 16 + l15][ks * 32 + lg * 8];
        #pragma unroll
        for (int m = 0; m < 4; ++m)
            #pragma unroll
            for (int n = 0; n < 2; ++n)
                acc[m][n] = __builtin_amdgcn_mfma_f32_16x16x32_bf16(af[m], bfv[n], acc[m][n], 0, 0, 0);
    }

    unsigned short* sp = sig + (size_t)b * SD + 128;
    #pragma unroll
    for (int m = 0; m < 4; ++m)
        #pragma unroll
        for (int n = 0; n < 2; ++n)
            #pragma unroll
            for (int rr = 0; rr < 4; ++rr)
                sp[(size_t)(wm * 64 + m * 16 + lg * 4 + rr) * 128 + wn * 32 + n * 16 + l15]
                    = bf1(acc[m][n][rr]);
}

// ---------------------------------------------------------------------------
// K2: split-K GEMM, BM=256 (W read ONCE). grid 256 = 32 ch x 8 nt, block 512
// = 8 waves, 1 block/CU all-resident. Per block: 256 rows x 32 cols, nsub
// 4-5 sub-stages of K=128. Single reg set, early-issue prefetch (spill-safe):
// LOADG(0); for s { WRITE; bar; LOADG(s+1); COMPUTE; bar; }.
// Partial packed bf16 row-pairs [rp][ch][col].
// ---------------------------------------------------------------------------
__global__ __launch_bounds__(512) void k_gemm(const unsigned short* __restrict__ sig,
                                              const float* __restrict__ W2,
                                              const float* __restrict__ Ws,
                                              unsigned* __restrict__ partial_p) {
    __shared__ unsigned short As[256 * 128];   // 64 KB, swizzled
    __shared__ unsigned short Bs[32 * 128];    // 8 KB, swizzled (B^T: [col][k])

    // XCD swizzle, nwg=256 (q=32 exact): ch's 8 nt-siblings -> same XCD
    int p = blockIdx.x;
    int lid = (p & 7) * 32 + (p >> 3);
    int ch = lid >> 3;
    int nt = lid & 7;
    const float* W = (nt < 4) ? W2 : Ws;
    int ntc = (nt & 3) * 32;                   // col offset within W
    int kb0 = ch * 512;
    int nsub = (ch == 31) ? 5 : 4;

    int tid = threadIdx.x;
    int w = tid >> 6, lane = tid & 63;
    int l15 = lane & 15, lg = lane >> 4;

    // staging coords
    int arow = tid >> 1;                       // 0..255
    int ah   = (tid & 1) * 64;                 // k-half base (64 k each)
    int asw  = (arow & 7) << 3;
    int bk   = tid >> 2;                       // 0..127
    int bc0  = (tid & 3) * 8;                  // 8 cols each

    f32x4 acc00 = (f32x4){0.f,0.f,0.f,0.f}, acc01 = (f32x4){0.f,0.f,0.f,0.f};
    f32x4 acc10 = (f32x4){0.f,0.f,0.f,0.f}, acc11 = (f32x4){0.f,0.f,0.f,0.f};

    uint4 aR[8];
    f32x4 bR[2];

#define LOADG(s)                                                                   \
    {                                                                              \
        int kb = kb0 + (s) * 128;                                                  \
        const unsigned short* asrc = sig + (size_t)arow * SD + kb + ah;            \
        _Pragma("unroll")                                                          \
        for (int j = 0; j < 8; ++j) aR[j] = *(const uint4*)(asrc + j * 8);         \
        const float* wp = W + (size_t)(kb + bk) * 128 + ntc + bc0;                 \
        bR[0] = *(const f32x4*)wp;                                                 \
        bR[1] = *(const f32x4*)(wp + 4);                                           \
    }

#define WRITELDS()                                                                 \
    {                                                                              \
        _Pragma("unroll")                                                          \
        for (int j = 0; j < 8; ++j)                                                \
            *(uint4*)&As[arow * 128 + ((ah + j * 8) ^ asw)] = aR[j];               \
        _Pragma("unroll")                                                          \
        for (int u = 0; u < 8; ++u) {                                              \
            int c = bc0 + u;                                                       \
            Bs[c * 128 + (bk ^ ((c & 7) << 3))] = bf1(bR[u >> 2][u & 3]);          \
        }                                                                          \
    }

#define COMPUTE()                                                                  \
    {                                                                              \
        _Pragma("unroll")                                                          \
        for (int ks = 0; ks < 4; ++ks) {                                           \
            int ko = ks * 32 + lg * 8;                                             \
            int row0 = w * 32 + l15, row1 = row0 + 16;                             \
            int col0 = l15,          col1 = 16 + l15;                              \
            bf16x8 a0 = *(const bf16x8*)&As[row0 * 128 + (ko ^ ((row0 & 7) << 3))];\
            bf16x8 a1 = *(const bf16x8*)&As[row1 * 128 + (ko ^ ((row1 & 7) << 3))];\
            bf16x8 b0 = *(const bf16x8*)&Bs[col0 * 128 + (ko ^ ((col0 & 7) << 3))];\
            bf16x8 b1 = *(const bf16x8*)&Bs[col1 * 128 + (ko ^ ((col1 & 7) << 3))];\
            acc00 = __builtin_amdgcn_mfma_f32_16x16x32_bf16(a0, b0, acc00, 0, 0, 0); \
            acc01 = __builtin_amdgcn_mfma_f32_16x16x32_bf16(a0, b1, acc01, 0, 0, 0); \
            acc10 = __builtin_amdgcn_mfma_f32_16x16x32_bf16(a1, b0, acc10, 0, 0, 0); \
            acc11 = __builtin_amdgcn_mfma_f32_16x16x32_bf16(a1, b1, acc11, 0, 0, 0); \
        }                                                                          \
    }

    LOADG(0);
    for (int s = 0; s < nsub; ++s) {
        WRITELDS();
        __syncthreads();
        if (s + 1 < nsub) LOADG(s + 1);    // issue next loads; overlap COMPUTE
        COMPUTE();
        __syncthreads();
    }
#undef LOADG
#undef WRITELDS
#undef COMPUTE

    // packed bf16 store: layout [rp][ch][col]
    #pragma unroll
    for (int fm = 0; fm < 2; ++fm) {
        int rp = w * 16 + fm * 8 + lg * 2;
        f32x4 an0 = fm ? acc10 : acc00;
        f32x4 an1 = fm ? acc11 : acc01;
        #pragma unroll
        for (int n = 0; n < 2; ++n) {
            int colg = nt * 32 + n * 16 + l15;
            f32x4 a = n ? an1 : an0;
            partial_p[(size_t)rp * RPSTRIDE + ch * 256 + colg]       = bfpack(a[0], a[1]);
            partial_p[(size_t)(rp + 1) * RPSTRIDE + ch * 256 + colg] = bfpack(a[2], a[3]);
        }
    }
}

// ---------------------------------------------------------------------------
// K3: fused tail. Reduce packed partials + GRN + LN + softmax (shuffle
// reductions) + dense MFMA. grid 256 (batch), block 512.
// ---------------------------------------------------------------------------
__global__ __launch_bounds__(512) void k_tail(const unsigned* __restrict__ partial_p,
                                              const unsigned short* __restrict__ xbf,
                                              const unsigned short* __restrict__ WdTg,
                                              const float* __restrict__ b2,
                                              const float* __restrict__ W1,
                                              const float* __restrict__ b1,
                                              const float* __restrict__ Wg,
                                              const float* __restrict__ bg,
                                              const float* __restrict__ Wv,
                                              const float* __restrict__ bv,
                                              const float* __restrict__ bs,
                                              const float* __restrict__ gamma,
                                              const float* __restrict__ beta,
                                              const float* __restrict__ bd,
                                              float* __restrict__ out) {
    __shared__ float hs[128], ss[128], h2s[128];
    __shared__ float red4[4][128], rtmp[2][256];
    __shared__ float wts[128];
    __shared__ float wred[2][4];

    int b = blockIdx.x, tid = threadIdx.x;
    int lane = tid & 63;
    int l15 = lane & 15, lg = lane >> 4;

    {   // split-K reduce over 32 chunks (contiguous [ch][col] span), unpack
        int c = tid & 255, h = tid >> 8;
        float s = 0.f;
        const unsigned* Pp = partial_p + (size_t)(b >> 1) * RPSTRIDE + c;
        bool hi = (b & 1) != 0;
        #pragma unroll 8
        for (int ch = h; ch < NCH; ch += 2) {
            unsigned u = Pp[ch * 256];
            unsigned hw = hi ? (u & 0xffff0000u) : (u << 16);
            s += __builtin_bit_cast(float, hw);
        }
        rtmp[h][c] = s;
    }
    __syncthreads();
    if (tid < 256) {
        float rsum = rtmp[0][tid] + rtmp[1][tid];
        if (tid < 128) {
            float hp = rsum + b2[tid];
            hs[tid] = hp > 0.f ? hp : expm1f(hp);
        } else {
            ss[tid - 128] = rsum + bs[tid - 128];
        }
    }
    __syncthreads();

    int c = tid & 127;
    {   // h2 = h1 @ W1 + b1, k split in 4 quarters
        int qt = tid >> 7;
        float s = 0.f;
        int kbq = qt * 32;
        #pragma unroll 8
        for (int k = 0; k < 32; ++k) s += hs[kbq + k] * W1[(size_t)(kbq + k) * 128 + c];
        red4[qt][c] = s;
    }
    __syncthreads();
    if (tid < 128)
        h2s[tid] = red4[0][tid] + red4[1][tid] + red4[2][tid] + red4[3][tid] + b1[tid];
    __syncthreads();
    {   // gate / value, k split in halves
        int idx = tid >> 7, sel = idx & 1, kh = idx >> 1;
        const float* Wx = sel ? Wv : Wg;
        float s = 0.f;
        int kbq = kh * 64;
        #pragma unroll 8
        for (int k = 0; k < 64; ++k) s += h2s[kbq + k] * Wx[(size_t)(kbq + k) * 128 + c];
        red4[idx][c] = s;
    }
    __syncthreads();

    // y, LN, softmax via wave-shuffle reductions (threads 0..127 = waves 0,1)
    float yv = 0.f, yn = 0.f, e = 0.f;
    if (tid < 128) {
        float g = 1.f / (1.f + expf(-(red4[0][c] + red4[2][c] + bg[c])));
        float v = red4[1][c] + red4[3][c] + bv[c];
        yv = ss[c] + g * v;
        float s1 = yv, s2 = yv * yv;
        #pragma unroll
        for (int off = 1; off < 64; off <<= 1) {
            s1 += __shfl_xor(s1, off, 64);
            s2 += __shfl_xor(s2, off, 64);
        }
        if (lane == 0) { wred[0][tid >> 6] = s1; wred[1][tid >> 6] = s2; }
    }
    __syncthreads();
    if (tid < 128) {
        float sum = wred[0][0] + wred[0][1];
        float sq  = wred[1][0] + wred[1][1];
        float mu = sum * (1.f / 128.f);
        float var = sq * (1.f / 128.f) - mu * mu;
        float rs = rsqrtf(var + LN_EPS);
        yn = (yv - mu) * rs * gamma[c] + beta[c];
        float m = yn;
        #pragma unroll
        for (int off = 1; off < 64; off <<= 1) m = fmaxf(m, __shfl_xor(m, off, 64));
        if (lane == 0) wred[0][tid >> 6] = m;
    }
    __syncthreads();
    if (tid < 128) {
        float m = fmaxf(wred[0][0], wred[0][1]);
        e = expf(yn - m);
        float s = e;
        #pragma unroll
        for (int off = 1; off < 64; off <<= 1) s += __shfl_xor(s, off, 64);
        if (lane == 0) wred[1][tid >> 6] = s;
    }
    __syncthreads();
    if (tid < 128) {
        float se = wred[1][0] + wred[1][1];
        wts[c] = e / se;
    }
    __syncthreads();

    // dense: out[t][d] = (sum_k xbf[t][k] WdTg[d][k] + bd[d]) * wts[d]
    int w4 = tid >> 6;
    const unsigned short* xrow = xbf + (size_t)b * 8192;
    f32x4 dacc[4];
    #pragma unroll
    for (int fm = 0; fm < 4; ++fm) dacc[fm] = (f32x4){0.f, 0.f, 0.f, 0.f};
    #pragma unroll
    for (int ks = 0; ks < 4; ++ks) {
        bf16x8 av[4], bv2;
        #pragma unroll
        for (int fm = 0; fm < 4; ++fm)
            av[fm] = *(const bf16x8*)(xrow + (size_t)(fm * 16 + l15) * 128 + ks * 32 + lg * 8);
        bv2 = *(const bf16x8*)(WdTg + (size_t)(w4 * 16 + l15) * 128 + ks * 32 + lg * 8);
        #pragma unroll
        for (int fm = 0; fm < 4; ++fm)
            dacc[fm] = __builtin_amdgcn_mfma_f32_16x16x32_bf16(av[fm], bv2, dacc[fm], 0, 0, 0);
    }
    int dcol = w4 * 16 + l15;
    float bdv = bd[dcol], wtv = wts[dcol];
    #pragma unroll
    for (int fm = 0; fm < 4; ++fm)
        #pragma unroll
        for (int rr = 0; rr < 4; ++rr) {
            int t = fm * 16 + lg * 4 + rr;
            out[(size_t)b * 8192 + (size_t)t * 128 + dcol] = (dacc[fm][rr] + bdv) * wtv;
        }
}

// ---------------------------------------------------------------------------
extern "C" void kernel_launch(void* const* d_in, const int* in_sizes, int n_in,
                              void* d_out, int out_size, void* d_ws, size_t ws_size,
                              hipStream_t stream) {
    const float* inputs = (const float*)d_in[0];
    const float* tk     = (const float*)d_in[1];
    const float* Wd     = (const float*)d_in[2];
    const float* bd     = (const float*)d_in[3];
    const float* W2     = (const float*)d_in[4];
    const float* b2     = (const float*)d_in[5];
    const float* W1     = (const float*)d_in[6];
    const float* b1     = (const float*)d_in[7];
    const float* Wg     = (const float*)d_in[8];
    const float* bg     = (const float*)d_in[9];
    const float* Wv     = (const float*)d_in[10];
    const float* bv     = (const float*)d_in[11];
    const float* Wsk    = (const float*)d_in[12];
    const float* bs     = (const float*)d_in[13];
    const float* gamma  = (const float*)d_in[14];
    const float* beta   = (const float*)d_in[15];
    float* out = (float*)d_out;

    char* ws = (char*)d_ws;
    unsigned short* sig  = (unsigned short*)ws;                 //  8,454,144 B
    unsigned* partial_p  = (unsigned*)(ws + 8454144);           //  4,194,304 B
    unsigned short* xbf  = (unsigned short*)(ws + 12648448);    //  4,194,304 B
    unsigned short* WdTg = (unsigned short*)(ws + 16842752);    //     32,768 B

    k_sig <<<257, 512, 0, stream>>>(inputs, tk, Wd, sig, xbf, WdTg);
    k_gemm<<<256, 512, 0, stream>>>(sig, W2, Wsk, partial_p);
    k_tail<<<256, 512, 0, stream>>>(partial_p, xbf, WdTg, b2, W1, b1, Wg, bg, Wv, bv,
                                    bs, gamma, beta, bd, out);
}

// Round 11
// 43.038 us; speedup vs baseline: 1.4317x; 1.4317x over previous
//
#include <hip/hip_runtime.h>
#include <math.h>

#define SD 16512            // 128 + 128*128
#define NCH 32              // K-chunks (31 x 512 + 1 x 640)
#define NKB 516             // k-blocks of 32 (516*32 = 16512)
#define RPSTRIDE 8192       // partial: [rowpair 128][ch 32][col 256] u32
#define LN_EPS 1e-5f

typedef __attribute__((ext_vector_type(4))) float f32x4;
typedef __attribute__((ext_vector_type(8))) short bf16x8;

__device__ __forceinline__ unsigned bfpack(float lo, float hi) {
    unsigned a = __builtin_bit_cast(unsigned, lo);
    unsigned b = __builtin_bit_cast(unsigned, hi);
    a = (a + 0x7FFFu + ((a >> 16) & 1u)) >> 16;
    b = (b + 0x7FFFu + ((b >> 16) & 1u)) >> 16;
    return a | (b << 16);
}
__device__ __forceinline__ unsigned short bf1(float x) {
    unsigned a = __builtin_bit_cast(unsigned, x);
    return (unsigned short)((a + 0x7FFFu + ((a >> 16) & 1u)) >> 16);
}

// ---------------------------------------------------------------------------
// K1: grid 1289 x 512.
//  p < 256      : batch block -> sigF (fragment-tiled signature), xbf.
//  256..1287    : W2/Ws transpose tile -> WTgF[mat][kblk][col 128][32k] bf16.
//  p == 1288    : WdTg[d][k] prep.
// sigF layout: [kblk 516][row=batch 256][32k] bf16. element (k,b) at
// (k>>5)*8192 + b*32 + (k&31). A-fragment read = contiguous 1KB per wave.
// ---------------------------------------------------------------------------
__global__ __launch_bounds__(512) void k_sig(const float* __restrict__ x,
                                             const float* __restrict__ tk,
                                             const float* __restrict__ Wd,
                                             const float* __restrict__ W2,
                                             const float* __restrict__ Ws,
                                             unsigned short* __restrict__ sigF,
                                             unsigned short* __restrict__ WTgF,
                                             unsigned short* __restrict__ xbf,
                                             unsigned short* __restrict__ WdTg) {
    __shared__ union {
        struct { unsigned short Ut[128][72]; unsigned short DXt[128][72]; float tks[64]; } s;
        struct { float T[32][132]; } t;
    } sm;
    int tid = threadIdx.x;
    int p = blockIdx.x;

    if (p >= 256 && p < 1288) {
        // ---- W transpose tile: 32 k-rows x 128 cols -> bf16 [col][32k] ----
        int q = p - 256;
        int mat = q & 1, kblk = q >> 1;
        int k0 = kblk * 32;
        const float* Wm = mat ? Ws : W2;
        {
            int kk = tid >> 4, c0 = (tid & 15) * 8;
            const float* src = Wm + (size_t)(k0 + kk) * 128 + c0;
            f32x4 v0 = *(const f32x4*)src;
            f32x4 v1 = *(const f32x4*)(src + 4);
            #pragma unroll
            for (int j = 0; j < 4; ++j) sm.t.T[kk][c0 + j]     = v0[j];
            #pragma unroll
            for (int j = 0; j < 4; ++j) sm.t.T[kk][c0 + 4 + j] = v1[j];
        }
        __syncthreads();
        {
            int c = tid >> 2, h8 = (tid & 3) * 8;
            uint4 o;
            o.x = bfpack(sm.t.T[h8    ][c], sm.t.T[h8 + 1][c]);
            o.y = bfpack(sm.t.T[h8 + 2][c], sm.t.T[h8 + 3][c]);
            o.z = bfpack(sm.t.T[h8 + 4][c], sm.t.T[h8 + 5][c]);
            o.w = bfpack(sm.t.T[h8 + 6][c], sm.t.T[h8 + 7][c]);
            *(uint4*)&WTgF[((size_t)(mat * NKB + kblk) * 128 + c) * 32 + h8] = o;
        }
        return;
    }
    if (p == 1288) {
        // ---- WdTg[d][k] = bf16(Wd[k][d]) ----
        int d = tid & 127, kh = tid >> 7;          // kh 0..3, 32 k each
        unsigned* dst = (unsigned*)WdTg;
        for (int kk = 0; kk < 32; kk += 2) {
            int k = kh * 32 + kk;
            float v0 = Wd[(size_t)k * 128 + d];
            float v1 = Wd[(size_t)(k + 1) * 128 + d];
            dst[d * 64 + (k >> 1)] = bfpack(v0, v1);
        }
        return;
    }

    // ---- batch block ----
    int b = p;
    if (tid < 64) sm.s.tks[tid] = tk[tid];
    __syncthreads();

    const float* xb = x + (size_t)b * 8192;
    unsigned short* xbb = xbf + (size_t)b * 8192;
    int i = tid & 127, th = tid >> 7;              // th 0..3, 8 pairs each

    float x0 = sm.s.tks[0] * xb[i];
    float xa = sm.s.tks[th * 16] * xb[(size_t)(th * 16) * 128 + i];
    #pragma unroll
    for (int tp = 0; tp < 8; ++tp) {
        int pp = th * 8 + tp;
        int t0 = 2 * pp;
        float xv = sm.s.tks[t0 + 1] * xb[(size_t)(t0 + 1) * 128 + i];
        float dx0 = xv - xa, u0 = 0.5f * (xa + xv) - x0;
        float dx1, u1, xc;
        if (pp == 31) { dx1 = 0.f; u1 = 0.f; xc = 0.f; }
        else {
            xc = sm.s.tks[t0 + 2] * xb[(size_t)(t0 + 2) * 128 + i];
            dx1 = xc - xv; u1 = 0.5f * (xv + xc) - x0;
        }
        *(unsigned*)&sm.s.Ut[i][t0]  = bfpack(u0, u1);
        *(unsigned*)&sm.s.DXt[i][t0] = bfpack(dx0, dx1);
        xbb[(size_t)t0 * 128 + i]       = bf1(xa);
        xbb[(size_t)(t0 + 1) * 128 + i] = bf1(xv);
        if (pp == 31)   // S1: k = i
            sigF[(size_t)(i >> 5) * 8192 + b * 32 + (i & 31)] = bf1(xv - x0);
        xa = xc;
    }
    __syncthreads();

    // S2 = Ut(128 x 64k) @ DXt^T. 8 waves: 2M x 4N, wave tile 64x32.
    int w = tid >> 6, lane = tid & 63;
    int wm = w >> 2, wn = w & 3;
    int l15 = lane & 15, lg = lane >> 4;
    f32x4 acc[4][2];
    #pragma unroll
    for (int m = 0; m < 4; ++m)
        #pragma unroll
        for (int n = 0; n < 2; ++n) acc[m][n] = (f32x4){0.f, 0.f, 0.f, 0.f};

    #pragma unroll
    for (int ks = 0; ks < 2; ++ks) {
        bf16x8 af[4], bfv[2];
        #pragma unroll
        for (int m = 0; m < 4; ++m)
            af[m] = *(const bf16x8*)&sm.s.Ut[wm * 64 + m * 16 + l15][ks * 32 + lg * 8];
        #pragma unroll
        for (int n = 0; n < 2; ++n)
            bfv[n] = *(const bf16x8*)&sm.s.DXt[wn * 32 + n * 16 + l15][ks * 32 + lg * 8];
        #pragma unroll
        for (int m = 0; m < 4; ++m)
            #pragma unroll
            for (int n = 0; n < 2; ++n)
                acc[m][n] = __builtin_amdgcn_mfma_f32_16x16x32_bf16(af[m], bfv[n], acc[m][n], 0, 0, 0);
    }

    // S2 element (r, c): k = 128 + r*128 + c -> kblk = 4*(r+1) + wn, kpos = n*16+l15
    #pragma unroll
    for (int m = 0; m < 4; ++m)
        #pragma unroll
        for (int n = 0; n < 2; ++n)
            #pragma unroll
            for (int rr = 0; rr < 4; ++rr) {
                int r = wm * 64 + m * 16 + lg * 4 + rr;
                sigF[(size_t)(4 * (r + 1) + wn) * 8192 + b * 32 + n * 16 + l15]
                    = bf1(acc[m][n][rr]);
            }
}

// ---------------------------------------------------------------------------
// K2: split-K GEMM, NO LDS / NO barriers. grid 512 = 32ch x 2mt x 8nt, block
// 512 = 8 waves, 2 blocks/CU. Wave: 16 rows x 32 cols; per ks (32k): 3
// coalesced 1KB fragment loads + 2 MFMA. Partial packed bf16 [rp][ch][col].
// ---------------------------------------------------------------------------
__global__ __launch_bounds__(512) void k_gemm(const unsigned short* __restrict__ sigF,
                                              const unsigned short* __restrict__ WTgF,
                                              unsigned* __restrict__ partial_p) {
    int p = blockIdx.x;
    int lid = (p & 7) * 64 + (p >> 3);     // XCD swizzle, nwg=512 (q=64 exact)
    int ch = lid >> 4;
    int mt = (lid >> 3) & 1;
    int nt = lid & 7;
    int mat = nt >> 2, ncol = (nt & 3) * 32;
    int kblk0 = ch * 16;
    int nks = (ch == 31) ? 20 : 16;

    int tid = threadIdx.x;
    int w = tid >> 6, lane = tid & 63;
    int l15 = lane & 15, lg = lane >> 4;

    const unsigned short* A = sigF + (size_t)kblk0 * 8192
                            + (size_t)(mt * 128 + w * 16 + l15) * 32 + lg * 8;
    const unsigned short* B = WTgF + ((size_t)(mat * NKB + kblk0) * 128 + ncol + l15) * 32 + lg * 8;

    f32x4 acc0 = (f32x4){0.f, 0.f, 0.f, 0.f};
    f32x4 acc1 = (f32x4){0.f, 0.f, 0.f, 0.f};

    #pragma unroll 4
    for (int ks = 0; ks < nks; ++ks) {
        bf16x8 a  = *(const bf16x8*)(A + (size_t)ks * 8192);
        bf16x8 b0 = *(const bf16x8*)(B + (size_t)ks * 4096);
        bf16x8 b1 = *(const bf16x8*)(B + (size_t)ks * 4096 + 512);
        acc0 = __builtin_amdgcn_mfma_f32_16x16x32_bf16(a, b0, acc0, 0, 0, 0);
        acc1 = __builtin_amdgcn_mfma_f32_16x16x32_bf16(a, b1, acc1, 0, 0, 0);
    }

    // packed bf16 store: layout [rp][ch][col]
    int r0 = mt * 128 + w * 16 + lg * 4;
    int rp0 = r0 >> 1;
    #pragma unroll
    for (int n = 0; n < 2; ++n) {
        int colg = nt * 32 + n * 16 + l15;
        f32x4 a = n ? acc1 : acc0;
        partial_p[(size_t)rp0 * RPSTRIDE + ch * 256 + colg]       = bfpack(a[0], a[1]);
        partial_p[(size_t)(rp0 + 1) * RPSTRIDE + ch * 256 + colg] = bfpack(a[2], a[3]);
    }
}

// ---------------------------------------------------------------------------
// K3: fused tail. Reduce packed partials + GRN + LN + softmax (shuffle
// reductions) + dense MFMA. grid 256 (batch), block 512.
// ---------------------------------------------------------------------------
__global__ __launch_bounds__(512) void k_tail(const unsigned* __restrict__ partial_p,
                                              const unsigned short* __restrict__ xbf,
                                              const unsigned short* __restrict__ WdTg,
                                              const float* __restrict__ b2,
                                              const float* __restrict__ W1,
                                              const float* __restrict__ b1,
                                              const float* __restrict__ Wg,
                                              const float* __restrict__ bg,
                                              const float* __restrict__ Wv,
                                              const float* __restrict__ bv,
                                              const float* __restrict__ bs,
                                              const float* __restrict__ gamma,
                                              const float* __restrict__ beta,
                                              const float* __restrict__ bd,
                                              float* __restrict__ out) {
    __shared__ float hs[128], ss[128], h2s[128];
    __shared__ float red4[4][128], rtmp[2][256];
    __shared__ float wts[128];
    __shared__ float wred[2][4];

    int b = blockIdx.x, tid = threadIdx.x;
    int lane = tid & 63;
    int l15 = lane & 15, lg = lane >> 4;

    {   // split-K reduce over 32 chunks (contiguous span), unpack bf16 half
        int c = tid & 255, h = tid >> 8;
        float s = 0.f;
        const unsigned* Pp = partial_p + (size_t)(b >> 1) * RPSTRIDE + c;
        bool hi = (b & 1) != 0;
        #pragma unroll 8
        for (int ch = h; ch < NCH; ch += 2) {
            unsigned u = Pp[ch * 256];
            unsigned hw = hi ? (u & 0xffff0000u) : (u << 16);
            s += __builtin_bit_cast(float, hw);
        }
        rtmp[h][c] = s;
    }
    __syncthreads();
    if (tid < 256) {
        float rsum = rtmp[0][tid] + rtmp[1][tid];
        if (tid < 128) {
            float hp = rsum + b2[tid];
            hs[tid] = hp > 0.f ? hp : expm1f(hp);
        } else {
            ss[tid - 128] = rsum + bs[tid - 128];
        }
    }
    __syncthreads();

    int c = tid & 127;
    {   // h2 = h1 @ W1 + b1, k split in 4 quarters
        int qt = tid >> 7;
        float s = 0.f;
        int kbq = qt * 32;
        #pragma unroll 8
        for (int k = 0; k < 32; ++k) s += hs[kbq + k] * W1[(size_t)(kbq + k) * 128 + c];
        red4[qt][c] = s;
    }
    __syncthreads();
    if (tid < 128)
        h2s[tid] = red4[0][tid] + red4[1][tid] + red4[2][tid] + red4[3][tid] + b1[tid];
    __syncthreads();
    {   // gate / value, k split in halves
        int idx = tid >> 7, sel = idx & 1, kh = idx >> 1;
        const float* Wx = sel ? Wv : Wg;
        float s = 0.f;
        int kbq = kh * 64;
        #pragma unroll 8
        for (int k = 0; k < 64; ++k) s += h2s[kbq + k] * Wx[(size_t)(kbq + k) * 128 + c];
        red4[idx][c] = s;
    }
    __syncthreads();

    // y, LN, softmax via wave-shuffle reductions (threads 0..127 = waves 0,1)
    float yv = 0.f, yn = 0.f, e = 0.f;
    if (tid < 128) {
        float g = 1.f / (1.f + expf(-(red4[0][c] + red4[2][c] + bg[c])));
        float v = red4[1][c] + red4[3][c] + bv[c];
        yv = ss[c] + g * v;
        float s1 = yv, s2 = yv * yv;
        #pragma unroll
        for (int off = 1; off < 64; off <<= 1) {
            s1 += __shfl_xor(s1, off, 64);
            s2 += __shfl_xor(s2, off, 64);
        }
        if (lane == 0) { wred[0][tid >> 6] = s1; wred[1][tid >> 6] = s2; }
    }
    __syncthreads();
    if (tid < 128) {
        float sum = wred[0][0] + wred[0][1];
        float sq  = wred[1][0] + wred[1][1];
        float mu = sum * (1.f / 128.f);
        float var = sq * (1.f / 128.f) - mu * mu;
        float rs = rsqrtf(var + LN_EPS);
        yn = (yv - mu) * rs * gamma[c] + beta[c];
        float m = yn;
        #pragma unroll
        for (int off = 1; off < 64; off <<= 1) m = fmaxf(m, __shfl_xor(m, off, 64));
        if (lane == 0) wred[0][tid >> 6] = m;
    }
    __syncthreads();
    if (tid < 128) {
        float m = fmaxf(wred[0][0], wred[0][1]);
        e = expf(yn - m);
        float s = e;
        #pragma unroll
        for (int off = 1; off < 64; off <<= 1) s += __shfl_xor(s, off, 64);
        if (lane == 0) wred[1][tid >> 6] = s;
    }
    __syncthreads();
    if (tid < 128) {
        float se = wred[1][0] + wred[1][1];
        wts[c] = e / se;
    }
    __syncthreads();

    // dense: out[t][d] = (sum_k xbf[t][k] WdTg[d][k] + bd[d]) * wts[d]
    int w4 = tid >> 6;
    const unsigned short* xrow = xbf + (size_t)b * 8192;
    f32x4 dacc[4];
    #pragma unroll
    for (int fm = 0; fm < 4; ++fm) dacc[fm] = (f32x4){0.f, 0.f, 0.f, 0.f};
    #pragma unroll
    for (int ks = 0; ks < 4; ++ks) {
        bf16x8 av[4], bv2;
        #pragma unroll
        for (int fm = 0; fm < 4; ++fm)
            av[fm] = *(const bf16x8*)(xrow + (size_t)(fm * 16 + l15) * 128 + ks * 32 + lg * 8);
        bv2 = *(const bf16x8*)(WdTg + (size_t)(w4 * 16 + l15) * 128 + ks * 32 + lg * 8);
        #pragma unroll
        for (int fm = 0; fm < 4; ++fm)
            dacc[fm] = __builtin_amdgcn_mfma_f32_16x16x32_bf16(av[fm], bv2, dacc[fm], 0, 0, 0);
    }
    int dcol = w4 * 16 + l15;
    float bdv = bd[dcol], wtv = wts[dcol];
    #pragma unroll
    for (int fm = 0; fm < 4; ++fm)
        #pragma unroll
        for (int rr = 0; rr < 4; ++rr) {
            int t = fm * 16 + lg * 4 + rr;
            out[(size_t)b * 8192 + (size_t)t * 128 + dcol] = (dacc[fm][rr] + bdv) * wtv;
        }
}

// ---------------------------------------------------------------------------
extern "C" void kernel_launch(void* const* d_in, const int* in_sizes, int n_in,
                              void* d_out, int out_size, void* d_ws, size_t ws_size,
                              hipStream_t stream) {
    const float* inputs = (const float*)d_in[0];
    const float* tk     = (const float*)d_in[1];
    const float* Wd     = (const float*)d_in[2];
    const float* bd     = (const float*)d_in[3];
    const float* W2     = (const float*)d_in[4];
    const float* b2     = (const float*)d_in[5];
    const float* W1     = (const float*)d_in[6];
    const float* b1     = (const float*)d_in[7];
    const float* Wg     = (const float*)d_in[8];
    const float* bg     = (const float*)d_in[9];
    const float* Wv     = (const float*)d_in[10];
    const float* bv     = (const float*)d_in[11];
    const float* Wsk    = (const float*)d_in[12];
    const float* bs     = (const float*)d_in[13];
    const float* gamma  = (const float*)d_in[14];
    const float* beta   = (const float*)d_in[15];
    float* out = (float*)d_out;

    char* ws = (char*)d_ws;
    unsigned short* sigF = (unsigned short*)ws;                 //  8,454,144 B
    unsigned short* WTgF = (unsigned short*)(ws + 8454144);     //  8,454,144 B
    unsigned* partial_p  = (unsigned*)(ws + 16908288);          //  4,194,304 B
    unsigned short* xbf  = (unsigned short*)(ws + 21102592);    //  4,194,304 B
    unsigned short* WdTg = (unsigned short*)(ws + 25296896);    //     32,768 B

    k_sig <<<1289, 512, 0, stream>>>(inputs, tk, Wd, W2, Wsk, sigF, WTgF, xbf, WdTg);
    k_gemm<<<512, 512, 0, stream>>>(sigF, WTgF, partial_p);
    k_tail<<<256, 512, 0, stream>>>(partial_p, xbf, WdTg, b2, W1, b1, Wg, bg, Wv, bv,
                                    bs, gamma, beta, bd, out);
}

// Round 12
// 40.940 us; speedup vs baseline: 1.5051x; 1.0512x over previous
//
#include <hip/hip_runtime.h>
#include <math.h>

#define SD 16512            // 128 + 128*128
#define NCH 32              // K-chunks (31 x 512 + 1 x 640)
#define NKB 516             // k-blocks of 32
#define RPSTRIDE 8192       // partial: [rowpair 128][ch 32][col 256] u32
#define LN_EPS 1e-5f

typedef __attribute__((ext_vector_type(4))) float f32x4;
typedef __attribute__((ext_vector_type(8))) short bf16x8;

__device__ __forceinline__ unsigned bfpack(float lo, float hi) {
    unsigned a = __builtin_bit_cast(unsigned, lo);
    unsigned b = __builtin_bit_cast(unsigned, hi);
    a = (a + 0x7FFFu + ((a >> 16) & 1u)) >> 16;
    b = (b + 0x7FFFu + ((b >> 16) & 1u)) >> 16;
    return a | (b << 16);
}
__device__ __forceinline__ unsigned short bf1(float x) {
    unsigned a = __builtin_bit_cast(unsigned, x);
    return (unsigned short)((a + 0x7FFFu + ((a >> 16) & 1u)) >> 16);
}

// ---------------------------------------------------------------------------
// K1: signature via MFMA. grid 257 x 512: p<256 = batch (XCD-grouped);
// p==256 = WdTg prep. sigF fragment layout [kblk 516][b*32 + k&31] bf16.
// Batch->XCD grouping: b = (p&7)*32 + (p>>3) so consecutive batches share an
// XCD and their 64B sigF column-slices write-combine in L2.
// ---------------------------------------------------------------------------
__global__ __launch_bounds__(512) void k_sig(const float* __restrict__ x,
                                             const float* __restrict__ tk,
                                             const float* __restrict__ Wd,
                                             unsigned short* __restrict__ sigF,
                                             unsigned short* __restrict__ xbf,
                                             unsigned short* __restrict__ WdTg) {
    __shared__ unsigned short Ut[128][72];
    __shared__ unsigned short DXt[128][72];
    __shared__ float tks[64];
    int tid = threadIdx.x;
    int p = blockIdx.x;

    if (p == 256) {
        int d = tid & 127, kh = tid >> 7;          // kh 0..3, 32 k each
        unsigned* dst = (unsigned*)WdTg;
        for (int kk = 0; kk < 32; kk += 2) {
            int k = kh * 32 + kk;
            float v0 = Wd[(size_t)k * 128 + d];
            float v1 = Wd[(size_t)(k + 1) * 128 + d];
            dst[d * 64 + (k >> 1)] = bfpack(v0, v1);
        }
        return;
    }

    int b = (p & 7) * 32 + (p >> 3);               // XCD-grouped batch id

    if (tid < 64) tks[tid] = tk[tid];
    __syncthreads();

    const float* xb = x + (size_t)b * 8192;
    unsigned short* xbb = xbf + (size_t)b * 8192;
    int i = tid & 127, th = tid >> 7;              // th 0..3, 8 pairs each

    float x0 = tks[0] * xb[i];
    float xa = tks[th * 16] * xb[(size_t)(th * 16) * 128 + i];
    #pragma unroll
    for (int tp = 0; tp < 8; ++tp) {
        int pp = th * 8 + tp;
        int t0 = 2 * pp;
        float xv = tks[t0 + 1] * xb[(size_t)(t0 + 1) * 128 + i];
        float dx0 = xv - xa, u0 = 0.5f * (xa + xv) - x0;
        float dx1, u1, xc;
        if (pp == 31) { dx1 = 0.f; u1 = 0.f; xc = 0.f; }
        else {
            xc = tks[t0 + 2] * xb[(size_t)(t0 + 2) * 128 + i];
            dx1 = xc - xv; u1 = 0.5f * (xv + xc) - x0;
        }
        *(unsigned*)&Ut[i][t0]  = bfpack(u0, u1);
        *(unsigned*)&DXt[i][t0] = bfpack(dx0, dx1);
        xbb[(size_t)t0 * 128 + i]       = bf1(xa);
        xbb[(size_t)(t0 + 1) * 128 + i] = bf1(xv);
        if (pp == 31)   // S1: k = i
            sigF[(size_t)(i >> 5) * 8192 + b * 32 + (i & 31)] = bf1(xv - x0);
        xa = xc;
    }
    __syncthreads();

    // S2 = Ut(128 x 64k) @ DXt^T. 8 waves: 2M x 4N, wave tile 64x32.
    int w = tid >> 6, lane = tid & 63;
    int wm = w >> 2, wn = w & 3;
    int l15 = lane & 15, lg = lane >> 4;
    f32x4 acc[4][2];
    #pragma unroll
    for (int m = 0; m < 4; ++m)
        #pragma unroll
        for (int n = 0; n < 2; ++n) acc[m][n] = (f32x4){0.f, 0.f, 0.f, 0.f};

    #pragma unroll
    for (int ks = 0; ks < 2; ++ks) {
        bf16x8 af[4], bfv[2];
        #pragma unroll
        for (int m = 0; m < 4; ++m)
            af[m] = *(const bf16x8*)&Ut[wm * 64 + m * 16 + l15][ks * 32 + lg * 8];
        #pragma unroll
        for (int n = 0; n < 2; ++n)
            bfv[n] = *(const bf16x8*)&DXt[wn * 32 + n * 16 + l15][ks * 32 + lg * 8];
        #pragma unroll
        for (int m = 0; m < 4; ++m)
            #pragma unroll
            for (int n = 0; n < 2; ++n)
                acc[m][n] = __builtin_amdgcn_mfma_f32_16x16x32_bf16(af[m], bfv[n], acc[m][n], 0, 0, 0);
    }

    // S2 element (r, c): k = 128 + r*128 + c -> kblk = 4*(r+1) + wn, kpos = n*16+l15
    #pragma unroll
    for (int m = 0; m < 4; ++m)
        #pragma unroll
        for (int n = 0; n < 2; ++n)
            #pragma unroll
            for (int rr = 0; rr < 4; ++rr) {
                int r = wm * 64 + m * 16 + lg * 4 + rr;
                sigF[(size_t)(4 * (r + 1) + wn) * 8192 + b * 32 + n * 16 + l15]
                    = bf1(acc[m][n][rr]);
            }
}

// ---------------------------------------------------------------------------
// K2: split-K GEMM. grid 512 = 32ch x 2mt x 8nt, block 512 = 8 waves,
// 2 blocks/CU. A = direct coalesced fragment loads from sigF (no LDS).
// B = W2/Ws f32 staged ONCE per block -> LDS [col 32][k 512/640] bf16,
// ^((col&15)<<4) swizzle. Per ks: 1 A load + 2 LDS B-frag reads + 2 MFMA.
// Partial packed bf16 [rp][ch][col].
// ---------------------------------------------------------------------------
__global__ __launch_bounds__(512) void k_gemm(const unsigned short* __restrict__ sigF,
                                              const float* __restrict__ W2,
                                              const float* __restrict__ Ws,
                                              unsigned* __restrict__ partial_p) {
    __shared__ unsigned short Bs[32 * 640];    // 40 KB, [col][k] swizzled

    int p = blockIdx.x;
    int lid = (p & 7) * 64 + (p >> 3);     // XCD swizzle, nwg=512 (q=64 exact)
    int ch = lid >> 4;
    int mt = (lid >> 3) & 1;
    int nt = lid & 7;
    const float* W = (nt < 4) ? W2 : Ws;
    int ntc = (nt & 3) * 32;
    int kblk0 = ch * 16;
    int nks = (ch == 31) ? 20 : 16;
    int nk = nks * 32;
    int kb0 = kblk0 * 32;

    int tid = threadIdx.x;
    int w = tid >> 6, lane = tid & 63;
    int l15 = lane & 15, lg = lane >> 4;

    // ---- stage B: rows kb0..kb0+nk of W, cols ntc..ntc+31 ----
    for (int kk = tid; kk < nk; kk += 512) {
        const float* wp = W + (size_t)(kb0 + kk) * 128 + ntc;
        float v[32];
        #pragma unroll
        for (int u = 0; u < 8; ++u) {
            f32x4 t = *(const f32x4*)(wp + u * 4);
            v[u * 4] = t[0]; v[u * 4 + 1] = t[1]; v[u * 4 + 2] = t[2]; v[u * 4 + 3] = t[3];
        }
        #pragma unroll
        for (int c = 0; c < 32; ++c) {
            int byteoff = (c * 1280 + kk * 2) ^ ((c & 15) << 4);
            *(unsigned short*)((char*)Bs + byteoff) = bf1(v[c]);
        }
    }
    __syncthreads();

    const unsigned short* A = sigF + (size_t)kblk0 * 8192
                            + (size_t)(mt * 128 + w * 16 + l15) * 32 + lg * 8;

    f32x4 acc0 = (f32x4){0.f, 0.f, 0.f, 0.f};
    f32x4 acc1 = (f32x4){0.f, 0.f, 0.f, 0.f};

    #pragma unroll 4
    for (int ks = 0; ks < nks; ++ks) {
        bf16x8 a = *(const bf16x8*)(A + (size_t)ks * 8192);
        int kof = (ks * 32 + lg * 8) * 2;
        int c0 = l15, c1 = 16 + l15;
        bf16x8 b0 = *(const bf16x8*)((const char*)Bs + ((c0 * 1280 + kof) ^ ((c0 & 15) << 4)));
        bf16x8 b1 = *(const bf16x8*)((const char*)Bs + ((c1 * 1280 + kof) ^ ((c1 & 15) << 4)));
        acc0 = __builtin_amdgcn_mfma_f32_16x16x32_bf16(a, b0, acc0, 0, 0, 0);
        acc1 = __builtin_amdgcn_mfma_f32_16x16x32_bf16(a, b1, acc1, 0, 0, 0);
    }

    // packed bf16 store: layout [rp][ch][col]
    int r0 = mt * 128 + w * 16 + lg * 4;
    int rp0 = r0 >> 1;
    #pragma unroll
    for (int n = 0; n < 2; ++n) {
        int colg = nt * 32 + n * 16 + l15;
        f32x4 a = n ? acc1 : acc0;
        partial_p[(size_t)rp0 * RPSTRIDE + ch * 256 + colg]       = bfpack(a[0], a[1]);
        partial_p[(size_t)(rp0 + 1) * RPSTRIDE + ch * 256 + colg] = bfpack(a[2], a[3]);
    }
}

// ---------------------------------------------------------------------------
// K3: fused tail. Reduce packed partials + GRN + LN + softmax (shuffle
// reductions) + dense MFMA. grid 256 (batch), block 512.
// ---------------------------------------------------------------------------
__global__ __launch_bounds__(512) void k_tail(const unsigned* __restrict__ partial_p,
                                              const unsigned short* __restrict__ xbf,
                                              const unsigned short* __restrict__ WdTg,
                                              const float* __restrict__ b2,
                                              const float* __restrict__ W1,
                                              const float* __restrict__ b1,
                                              const float* __restrict__ Wg,
                                              const float* __restrict__ bg,
                                              const float* __restrict__ Wv,
                                              const float* __restrict__ bv,
                                              const float* __restrict__ bs,
                                              const float* __restrict__ gamma,
                                              const float* __restrict__ beta,
                                              const float* __restrict__ bd,
                                              float* __restrict__ out) {
    __shared__ float hs[128], ss[128], h2s[128];
    __shared__ float red4[4][128], rtmp[2][256];
    __shared__ float wts[128];
    __shared__ float wred[2][4];

    int b = blockIdx.x, tid = threadIdx.x;
    int lane = tid & 63;
    int l15 = lane & 15, lg = lane >> 4;

    {   // split-K reduce over 32 chunks (contiguous span), unpack bf16 half
        int c = tid & 255, h = tid >> 8;
        float s = 0.f;
        const unsigned* Pp = partial_p + (size_t)(b >> 1) * RPSTRIDE + c;
        bool hi = (b & 1) != 0;
        #pragma unroll 8
        for (int ch = h; ch < NCH; ch += 2) {
            unsigned u = Pp[ch * 256];
            unsigned hw = hi ? (u & 0xffff0000u) : (u << 16);
            s += __builtin_bit_cast(float, hw);
        }
        rtmp[h][c] = s;
    }
    __syncthreads();
    if (tid < 256) {
        float rsum = rtmp[0][tid] + rtmp[1][tid];
        if (tid < 128) {
            float hp = rsum + b2[tid];
            hs[tid] = hp > 0.f ? hp : expm1f(hp);
        } else {
            ss[tid - 128] = rsum + bs[tid - 128];
        }
    }
    __syncthreads();

    int c = tid & 127;
    {   // h2 = h1 @ W1 + b1, k split in 4 quarters
        int qt = tid >> 7;
        float s = 0.f;
        int kbq = qt * 32;
        #pragma unroll 8
        for (int k = 0; k < 32; ++k) s += hs[kbq + k] * W1[(size_t)(kbq + k) * 128 + c];
        red4[qt][c] = s;
    }
    __syncthreads();
    if (tid < 128)
        h2s[tid] = red4[0][tid] + red4[1][tid] + red4[2][tid] + red4[3][tid] + b1[tid];
    __syncthreads();
    {   // gate / value, k split in halves
        int idx = tid >> 7, sel = idx & 1, kh = idx >> 1;
        const float* Wx = sel ? Wv : Wg;
        float s = 0.f;
        int kbq = kh * 64;
        #pragma unroll 8
        for (int k = 0; k < 64; ++k) s += h2s[kbq + k] * Wx[(size_t)(kbq + k) * 128 + c];
        red4[idx][c] = s;
    }
    __syncthreads();

    // y, LN, softmax via wave-shuffle reductions (threads 0..127 = waves 0,1)
    float yv = 0.f, yn = 0.f, e = 0.f;
    if (tid < 128) {
        float g = 1.f / (1.f + expf(-(red4[0][c] + red4[2][c] + bg[c])));
        float v = red4[1][c] + red4[3][c] + bv[c];
        yv = ss[c] + g * v;
        float s1 = yv, s2 = yv * yv;
        #pragma unroll
        for (int off = 1; off < 64; off <<= 1) {
            s1 += __shfl_xor(s1, off, 64);
            s2 += __shfl_xor(s2, off, 64);
        }
        if (lane == 0) { wred[0][tid >> 6] = s1; wred[1][tid >> 6] = s2; }
    }
    __syncthreads();
    if (tid < 128) {
        float sum = wred[0][0] + wred[0][1];
        float sq  = wred[1][0] + wred[1][1];
        float mu = sum * (1.f / 128.f);
        float var = sq * (1.f / 128.f) - mu * mu;
        float rs = rsqrtf(var + LN_EPS);
        yn = (yv - mu) * rs * gamma[c] + beta[c];
        float m = yn;
        #pragma unroll
        for (int off = 1; off < 64; off <<= 1) m = fmaxf(m, __shfl_xor(m, off, 64));
        if (lane == 0) wred[0][tid >> 6] = m;
    }
    __syncthreads();
    if (tid < 128) {
        float m = fmaxf(wred[0][0], wred[0][1]);
        e = expf(yn - m);
        float s = e;
        #pragma unroll
        for (int off = 1; off < 64; off <<= 1) s += __shfl_xor(s, off, 64);
        if (lane == 0) wred[1][tid >> 6] = s;
    }
    __syncthreads();
    if (tid < 128) {
        float se = wred[1][0] + wred[1][1];
        wts[c] = e / se;
    }
    __syncthreads();

    // dense: out[t][d] = (sum_k xbf[t][k] WdTg[d][k] + bd[d]) * wts[d]
    int w4 = tid >> 6;
    const unsigned short* xrow = xbf + (size_t)b * 8192;
    f32x4 dacc[4];
    #pragma unroll
    for (int fm = 0; fm < 4; ++fm) dacc[fm] = (f32x4){0.f, 0.f, 0.f, 0.f};
    #pragma unroll
    for (int ks = 0; ks < 4; ++ks) {
        bf16x8 av[4], bv2;
        #pragma unroll
        for (int fm = 0; fm < 4; ++fm)
            av[fm] = *(const bf16x8*)(xrow + (size_t)(fm * 16 + l15) * 128 + ks * 32 + lg * 8);
        bv2 = *(const bf16x8*)(WdTg + (size_t)(w4 * 16 + l15) * 128 + ks * 32 + lg * 8);
        #pragma unroll
        for (int fm = 0; fm < 4; ++fm)
            dacc[fm] = __builtin_amdgcn_mfma_f32_16x16x32_bf16(av[fm], bv2, dacc[fm], 0, 0, 0);
    }
    int dcol = w4 * 16 + l15;
    float bdv = bd[dcol], wtv = wts[dcol];
    #pragma unroll
    for (int fm = 0; fm < 4; ++fm)
        #pragma unroll
        for (int rr = 0; rr < 4; ++rr) {
            int t = fm * 16 + lg * 4 + rr;
            out[(size_t)b * 8192 + (size_t)t * 128 + dcol] = (dacc[fm][rr] + bdv) * wtv;
        }
}

// ---------------------------------------------------------------------------
extern "C" void kernel_launch(void* const* d_in, const int* in_sizes, int n_in,
                              void* d_out, int out_size, void* d_ws, size_t ws_size,
                              hipStream_t stream) {
    const float* inputs = (const float*)d_in[0];
    const float* tk     = (const float*)d_in[1];
    const float* Wd     = (const float*)d_in[2];
    const float* bd     = (const float*)d_in[3];
    const float* W2     = (const float*)d_in[4];
    const float* b2     = (const float*)d_in[5];
    const float* W1     = (const float*)d_in[6];
    const float* b1     = (const float*)d_in[7];
    const float* Wg     = (const float*)d_in[8];
    const float* bg     = (const float*)d_in[9];
    const float* Wv     = (const float*)d_in[10];
    const float* bv     = (const float*)d_in[11];
    const float* Wsk    = (const float*)d_in[12];
    const float* bs     = (const float*)d_in[13];
    const float* gamma  = (const float*)d_in[14];
    const float* beta   = (const float*)d_in[15];
    float* out = (float*)d_out;

    char* ws = (char*)d_ws;
    unsigned short* sigF = (unsigned short*)ws;                 //  8,454,144 B
    unsigned* partial_p  = (unsigned*)(ws + 8454144);           //  4,194,304 B
    unsigned short* xbf  = (unsigned short*)(ws + 12648448);    //  4,194,304 B
    unsigned short* WdTg = (unsigned short*)(ws + 16842752);    //     32,768 B

    k_sig <<<257, 512, 0, stream>>>(inputs, tk, Wd, sigF, xbf, WdTg);
    k_gemm<<<512, 512, 0, stream>>>(sigF, W2, Wsk, partial_p);
    k_tail<<<256, 512, 0, stream>>>(partial_p, xbf, WdTg, b2, W1, b1, Wg, bg, Wv, bv,
                                    bs, gamma, beta, bd, out);
}